// Round 3
// baseline (263.166 us; speedup 1.0000x reference)
//
#include <hip/hip_runtime.h>
#include <hip/hip_bf16.h>
#include <math.h>

// Problem constants
#define BB   32
#define HN   12
#define N1   256
#define N2   320
#define SS   256
#define BH   (BB*HN)                 // 384
#define ROWS (BH*N1)                 // 98304 rows per tensor
#define N4PT ((size_t)ROWS*N2/4)     // float4 per tensor = 7,864,320

// Chunking: 4 chunks of 8 batches -> per-chunk working set ~126 MB << 256 MB L3
#define NCH     4
#define BC      (BB/NCH)             // 8 batches per chunk
#define BH_C    (BC*HN)              // 96
#define ROWS_C  (BH_C*N1)            // 24576 rows per tensor per chunk
#define N4PT_C  (ROWS_C*N2/4)        // 1,966,080 float4 per tensor per chunk
#define MOD_BLOCKS (2*N4PT_C/256)    // 15360
#define RM_BLOCKS  (2*ROWS_C/4)      // 12288 (one wave per row, 4 waves/block)

typedef float v4f __attribute__((ext_vector_type(4)));

// Fused kernel: blocks [0, modBlocks) modulate chunk c (reads should be L3
// hits, NT stores); blocks [modBlocks, ...) do rowmax of chunk c+1.
__global__ __launch_bounds__(256) void k_fused(
    const float* __restrict__ modRgb, const float* __restrict__ modTir,
    const float* __restrict__ grgb,  const float* __restrict__ gtir,
    v4f* __restrict__ outTir, v4f* __restrict__ outRgb,
    const float* __restrict__ rmRgb, const float* __restrict__ rmTir,
    float* __restrict__ mxr, float* __restrict__ mxt,
    int modBlocks)
{
    int blk = (int)blockIdx.x;
    if (blk < modBlocks) {
        int i = blk * 256 + (int)threadIdx.x;        // 0 .. 2*N4PT_C-1
        int isRgb = i >= N4PT_C;
        int j = isRgb ? i - N4PT_C : i;
        int row = j / 80;                            // N2/4 = 80 float4 per row
        float gate = isRgb ? grgb[row] : gtir[row];
        v4f a = ((const v4f*)(isRgb ? modRgb : modTir))[j];
        __builtin_nontemporal_store(a * gate, &(isRgb ? outRgb : outTir)[j]);
    } else {
        int wid  = ((blk - modBlocks) * 256 + (int)threadIdx.x) >> 6;
        int lane = threadIdx.x & 63;
        int isTir = wid >= ROWS_C;
        int row  = isTir ? wid - ROWS_C : wid;
        const v4f* p = (const v4f*)((isTir ? rmTir : rmRgb) + (size_t)row * N2);
        v4f a = p[lane];
        float m = fmaxf(fmaxf(a.x, a.y), fmaxf(a.z, a.w));
        if (lane < 16) {
            v4f bq = p[64 + lane];
            m = fmaxf(m, fmaxf(fmaxf(bq.x, bq.y), fmaxf(bq.z, bq.w)));
        }
#pragma unroll
        for (int off = 32; off; off >>= 1) m = fmaxf(m, __shfl_xor(m, off));
        if (lane == 0) (isTir ? mxt : mxr)[row] = m;
    }
}

// Per-chunk MLP: one block per (b,h). scatter -> LN(512) -> 512x256 relu ->
// 256x512 sigmoid -> gather gates. Split accumulators shorten dep chains.
__global__ __launch_bounds__(256) void k_mlp(
    const int*   __restrict__ gidx,                 // chunk-local batches
    const float* __restrict__ mxr, const float* __restrict__ mxt,
    const float* __restrict__ ln_g, const float* __restrict__ ln_b,
    const float* __restrict__ W1,  const float* __restrict__ b1,
    const float* __restrict__ W2,  const float* __restrict__ b2,
    float* __restrict__ grgb, float* __restrict__ gtir)
{
    __shared__ float v[2 * SS];
    __shared__ float hs[SS];
    __shared__ float gs[2 * SS];
    __shared__ float red[8];

    const int bh = (int)blockIdx.x;      // 0..95 chunk-local
    const int b  = bh / HN;              // chunk-local batch
    const int t  = (int)threadIdx.x;     // 0..255

    const int sidx = gidx[b * SS + t];

    v[t] = 0.f; v[t + SS] = 0.f;
    __syncthreads();
    v[sidx]      = mxr[bh * N1 + t];
    v[sidx + SS] = mxt[bh * N1 + t];
    __syncthreads();

    // LayerNorm over 512
    float x0 = v[t], x1 = v[t + SS];
    float s  = x0 + x1;
    float sq = x0 * x0 + x1 * x1;
#pragma unroll
    for (int off = 32; off; off >>= 1) {
        s  += __shfl_xor(s, off);
        sq += __shfl_xor(sq, off);
    }
    int wv = t >> 6;
    if ((t & 63) == 0) { red[wv] = s; red[4 + wv] = sq; }
    __syncthreads();
    s  = red[0] + red[1] + red[2] + red[3];
    sq = red[4] + red[5] + red[6] + red[7];
    const float mu   = s * (1.f / 512.f);
    const float var  = sq * (1.f / 512.f) - mu * mu;
    const float rstd = rsqrtf(var + 1e-5f);
    v[t]      = (x0 - mu) * rstd * ln_g[t]      + ln_b[t];
    v[t + SS] = (x1 - mu) * rstd * ln_g[t + SS] + ln_b[t + SS];
    __syncthreads();

    // GEMM1: hs[t] = relu(sum_e v[e]*W1[e*256+t] + b1[t]), two chains
    {
        float a0 = b1[t], a1 = 0.f;
#pragma unroll 8
        for (int e = 0; e < SS; ++e)       a0 = fmaf(v[e], W1[e * SS + t], a0);
#pragma unroll 8
        for (int e = SS; e < 2 * SS; ++e)  a1 = fmaf(v[e], W1[e * SS + t], a1);
        hs[t] = fmaxf(a0 + a1, 0.f);
    }
    __syncthreads();

    // GEMM2: gs[t], gs[t+256] = sigmoid(sum_f hs[f]*W2[f*512 + .] + b2)
    {
        float lo0 = b2[t], lo1 = 0.f, hi0 = b2[t + SS], hi1 = 0.f;
#pragma unroll 8
        for (int f = 0; f < 128; ++f) {
            float hv = hs[f];
            lo0 = fmaf(hv, W2[f * 2 * SS + t],      lo0);
            hi0 = fmaf(hv, W2[f * 2 * SS + t + SS], hi0);
        }
#pragma unroll 8
        for (int f = 128; f < SS; ++f) {
            float hv = hs[f];
            lo1 = fmaf(hv, W2[f * 2 * SS + t],      lo1);
            hi1 = fmaf(hv, W2[f * 2 * SS + t + SS], hi1);
        }
        gs[t]      = 1.f / (1.f + expf(-(lo0 + lo1)));
        gs[t + SS] = 1.f / (1.f + expf(-(hi0 + hi1)));
    }
    __syncthreads();

    grgb[bh * N1 + t] = gs[sidx];
    gtir[bh * N1 + t] = gs[sidx + SS];
}

extern "C" void kernel_launch(void* const* d_in, const int* in_sizes, int n_in,
                              void* d_out, int out_size, void* d_ws, size_t ws_size,
                              hipStream_t stream)
{
    const float* attn_rgb = (const float*)d_in[0];
    const float* attn_tir = (const float*)d_in[1];
    const int*   gidx     = (const int*)  d_in[2];
    const float* ln_g     = (const float*)d_in[3];
    const float* ln_b     = (const float*)d_in[4];
    const float* W1       = (const float*)d_in[5];
    const float* b1       = (const float*)d_in[6];
    const float* W2       = (const float*)d_in[7];
    const float* b2       = (const float*)d_in[8];

    float* ws   = (float*)d_ws;
    float* mxr  = ws;                  // [ROWS]
    float* mxt  = mxr + ROWS;          // [ROWS]
    float* grgb = mxt + ROWS;          // [ROWS]
    float* gtir = grgb + ROWS;         // [ROWS]

    v4f* outTir = (v4f*)d_out;         // tir_col first per reference return
    v4f* outRgb = outTir + N4PT;

    // A0: rowmax of chunk 0 only
    k_fused<<<RM_BLOCKS, 256, 0, stream>>>(
        nullptr, nullptr, nullptr, nullptr, nullptr, nullptr,
        attn_rgb, attn_tir, mxr, mxt, 0);

    for (int c = 0; c < NCH; ++c) {
        size_t ro = (size_t)c * ROWS_C;        // row offset
        size_t eo = ro * N2;                   // element offset into attn

        // B_c: MLP for chunk c
        k_mlp<<<BH_C, 256, 0, stream>>>(
            gidx + (size_t)c * BC * SS, mxr + ro, mxt + ro,
            ln_g, ln_b, W1, b1, W2, b2, grgb + ro, gtir + ro);

        // D_c: modulate chunk c (+ rowmax chunk c+1 if any)
        int hasNext = (c + 1 < NCH);
        size_t no = (size_t)(c + 1) * ROWS_C;
        int grid = MOD_BLOCKS + (hasNext ? RM_BLOCKS : 0);
        k_fused<<<grid, 256, 0, stream>>>(
            attn_rgb + eo, attn_tir + eo, grgb + ro, gtir + ro,
            outTir + (size_t)c * N4PT_C, outRgb + (size_t)c * N4PT_C,
            hasNext ? attn_rgb + no * N2 : nullptr,
            hasNext ? attn_tir + no * N2 : nullptr,
            hasNext ? mxr + no : nullptr,
            hasNext ? mxt + no : nullptr,
            MOD_BLOCKS);
    }
}

// Round 4
// 183.946 us; speedup vs baseline: 1.4307x; 1.4307x over previous
//
#include <hip/hip_runtime.h>
#include <hip/hip_bf16.h>
#include <math.h>

// Problem constants
#define BB   32
#define HN   12
#define N1   256
#define N2   320
#define SS   256
#define BH   (BB*HN)                 // 384
#define ROWS (BH*N1)                 // 98304 rows per tensor
#define R4   (N2/4)                  // 80 float4 per row
#define N4PT ((size_t)ROWS*R4)       // float4 per tensor = 7,864,320

typedef float v4f __attribute__((ext_vector_type(4)));

// ---- Kernel 1: rowmax + stage raw input into its final d_out location ----
// One wave per row. NT loads keep the streaming read out of L3 so the
// staging writes (normal stores) can stay resident (dirty) until k3.
__global__ __launch_bounds__(256) void k_stage(
    const float* __restrict__ rgb, const float* __restrict__ tir,
    float* __restrict__ mxr, float* __restrict__ mxt,
    v4f* __restrict__ outTir, v4f* __restrict__ outRgb)
{
    int wid  = ((int)blockIdx.x * 256 + (int)threadIdx.x) >> 6;
    int lane = threadIdx.x & 63;
    int isTir = wid >= ROWS;
    int row  = isTir ? wid - ROWS : wid;
    const v4f* p  = (const v4f*)((isTir ? tir : rgb) + (size_t)row * N2);
    v4f*       st = (isTir ? outTir : outRgb) + (size_t)row * R4;

    v4f a = __builtin_nontemporal_load(&p[lane]);
    st[lane] = a;
    float m = fmaxf(fmaxf(a.x, a.y), fmaxf(a.z, a.w));
    if (lane < 16) {
        v4f b = __builtin_nontemporal_load(&p[64 + lane]);
        st[64 + lane] = b;
        m = fmaxf(m, fmaxf(fmaxf(b.x, b.y), fmaxf(b.z, b.w)));
    }
#pragma unroll
    for (int off = 32; off; off >>= 1) m = fmaxf(m, __shfl_xor(m, off));
    if (lane == 0) (isTir ? mxt : mxr)[row] = m;
}

// ---- Kernel 2: scatter -> LayerNorm -> MLP -> gather gates (4 bh/block) ----
__global__ __launch_bounds__(256) void k_mlp(
    const int*   __restrict__ gidx,
    const float* __restrict__ mxr, const float* __restrict__ mxt,
    const float* __restrict__ ln_g, const float* __restrict__ ln_b,
    const float* __restrict__ W1,  const float* __restrict__ b1,
    const float* __restrict__ W2,  const float* __restrict__ b2,
    float* __restrict__ grgb, float* __restrict__ gtir)
{
    __shared__ float v[4][2 * SS];
    __shared__ float hs[4][SS];
    __shared__ float gs[4][2 * SS];

    const int t   = threadIdx.x;     // 0..255
    const int bh0 = blockIdx.x * 4;

#pragma unroll
    for (int r = 0; r < 4; ++r) { v[r][t] = 0.f; v[r][t + SS] = 0.f; }
    __syncthreads();
#pragma unroll
    for (int r = 0; r < 4; ++r) {
        int bh   = bh0 + r;
        int b    = bh / HN;
        int sidx = gidx[b * SS + t];
        v[r][sidx]      = mxr[bh * N1 + t];
        v[r][sidx + SS] = mxt[bh * N1 + t];
    }
    __syncthreads();

    // LayerNorm over 512: wave w handles row w (8 elements per lane)
    {
        int w = t >> 6, l = t & 63;
        float xs[8];
        float s = 0.f, sq = 0.f;
#pragma unroll
        for (int k = 0; k < 8; ++k) {
            xs[k] = v[w][l + 64 * k];
            s += xs[k]; sq = fmaf(xs[k], xs[k], sq);
        }
#pragma unroll
        for (int off = 32; off; off >>= 1) {
            s  += __shfl_xor(s, off);
            sq += __shfl_xor(sq, off);
        }
        float mu   = s * (1.f / 512.f);
        float var  = sq * (1.f / 512.f) - mu * mu;
        float rstd = rsqrtf(var + 1e-5f);
#pragma unroll
        for (int k = 0; k < 8; ++k) {
            int i = l + 64 * k;
            v[w][i] = (xs[k] - mu) * rstd * ln_g[i] + ln_b[i];
        }
    }
    __syncthreads();

    // GEMM1: hs[r][t] = relu(sum_e v[r][e] * W1[e*256+t] + b1[t])
    {
        float acc0 = b1[t], acc1 = acc0, acc2 = acc0, acc3 = acc0;
#pragma unroll 4
        for (int e4 = 0; e4 < 128; ++e4) {
            v4f v0 = *(const v4f*)&v[0][e4 * 4];
            v4f v1 = *(const v4f*)&v[1][e4 * 4];
            v4f v2 = *(const v4f*)&v[2][e4 * 4];
            v4f v3 = *(const v4f*)&v[3][e4 * 4];
            float w0 = W1[(e4 * 4 + 0) * SS + t];
            float w1 = W1[(e4 * 4 + 1) * SS + t];
            float w2 = W1[(e4 * 4 + 2) * SS + t];
            float w3 = W1[(e4 * 4 + 3) * SS + t];
            acc0 = fmaf(v0.x, w0, acc0); acc0 = fmaf(v0.y, w1, acc0);
            acc0 = fmaf(v0.z, w2, acc0); acc0 = fmaf(v0.w, w3, acc0);
            acc1 = fmaf(v1.x, w0, acc1); acc1 = fmaf(v1.y, w1, acc1);
            acc1 = fmaf(v1.z, w2, acc1); acc1 = fmaf(v1.w, w3, acc1);
            acc2 = fmaf(v2.x, w0, acc2); acc2 = fmaf(v2.y, w1, acc2);
            acc2 = fmaf(v2.z, w2, acc2); acc2 = fmaf(v2.w, w3, acc2);
            acc3 = fmaf(v3.x, w0, acc3); acc3 = fmaf(v3.y, w1, acc3);
            acc3 = fmaf(v3.z, w2, acc3); acc3 = fmaf(v3.w, w3, acc3);
        }
        hs[0][t] = fmaxf(acc0, 0.f);
        hs[1][t] = fmaxf(acc1, 0.f);
        hs[2][t] = fmaxf(acc2, 0.f);
        hs[3][t] = fmaxf(acc3, 0.f);
    }
    __syncthreads();

    // GEMM2: gs[r][t], gs[r][t+256] = sigmoid(sum_f hs[r][f] * W2[f*512+.] + b2)
    {
        float alo0 = b2[t],      alo1 = alo0, alo2 = alo0, alo3 = alo0;
        float ahi0 = b2[t + SS], ahi1 = ahi0, ahi2 = ahi0, ahi3 = ahi0;
#pragma unroll 4
        for (int f4 = 0; f4 < 64; ++f4) {
            v4f h0 = *(const v4f*)&hs[0][f4 * 4];
            v4f h1 = *(const v4f*)&hs[1][f4 * 4];
            v4f h2 = *(const v4f*)&hs[2][f4 * 4];
            v4f h3 = *(const v4f*)&hs[3][f4 * 4];
#pragma unroll
            for (int q = 0; q < 4; ++q) {
                int f = f4 * 4 + q;
                float wlo = W2[f * 2 * SS + t];
                float whi = W2[f * 2 * SS + t + SS];
                float e0 = (q == 0) ? h0.x : (q == 1) ? h0.y : (q == 2) ? h0.z : h0.w;
                float e1 = (q == 0) ? h1.x : (q == 1) ? h1.y : (q == 2) ? h1.z : h1.w;
                float e2 = (q == 0) ? h2.x : (q == 1) ? h2.y : (q == 2) ? h2.z : h2.w;
                float e3 = (q == 0) ? h3.x : (q == 1) ? h3.y : (q == 2) ? h3.z : h3.w;
                alo0 = fmaf(e0, wlo, alo0); ahi0 = fmaf(e0, whi, ahi0);
                alo1 = fmaf(e1, wlo, alo1); ahi1 = fmaf(e1, whi, ahi1);
                alo2 = fmaf(e2, wlo, alo2); ahi2 = fmaf(e2, whi, ahi2);
                alo3 = fmaf(e3, wlo, alo3); ahi3 = fmaf(e3, whi, ahi3);
            }
        }
        gs[0][t] = 1.f / (1.f + expf(-alo0)); gs[0][t + SS] = 1.f / (1.f + expf(-ahi0));
        gs[1][t] = 1.f / (1.f + expf(-alo1)); gs[1][t + SS] = 1.f / (1.f + expf(-ahi1));
        gs[2][t] = 1.f / (1.f + expf(-alo2)); gs[2][t + SS] = 1.f / (1.f + expf(-ahi2));
        gs[3][t] = 1.f / (1.f + expf(-alo3)); gs[3][t + SS] = 1.f / (1.f + expf(-ahi3));
    }
    __syncthreads();

#pragma unroll
    for (int r = 0; r < 4; ++r) {
        int bh   = bh0 + r;
        int b    = bh / HN;
        int sidx = gidx[b * SS + t];
        grgb[bh * N1 + t] = gs[r][sidx];
        gtir[bh * N1 + t] = gs[r][sidx + SS];
    }
}

// ---- Kernel 3: in-place scale of the staged copy in d_out ----
// One wave per row; gate is wave-uniform. Reads should hit dirty L3 lines
// written by k_stage; writes re-dirty the same lines (single writeback).
__global__ __launch_bounds__(256) void k_scale(
    const float* __restrict__ grgb, const float* __restrict__ gtir,
    v4f* __restrict__ outTir, v4f* __restrict__ outRgb)
{
    int wid  = ((int)blockIdx.x * 256 + (int)threadIdx.x) >> 6;
    int lane = threadIdx.x & 63;
    int isTir = wid >= ROWS;
    int row  = isTir ? wid - ROWS : wid;
    v4f*  o = (isTir ? outTir : outRgb) + (size_t)row * R4;
    float g = (isTir ? gtir : grgb)[row];

    v4f a = o[lane];
    o[lane] = a * g;
    if (lane < 16) {
        v4f b = o[64 + lane];
        o[64 + lane] = b * g;
    }
}

extern "C" void kernel_launch(void* const* d_in, const int* in_sizes, int n_in,
                              void* d_out, int out_size, void* d_ws, size_t ws_size,
                              hipStream_t stream)
{
    const float* attn_rgb = (const float*)d_in[0];
    const float* attn_tir = (const float*)d_in[1];
    const int*   gidx     = (const int*)  d_in[2];
    const float* ln_g     = (const float*)d_in[3];
    const float* ln_b     = (const float*)d_in[4];
    const float* W1       = (const float*)d_in[5];
    const float* b1       = (const float*)d_in[6];
    const float* W2       = (const float*)d_in[7];
    const float* b2       = (const float*)d_in[8];

    float* ws   = (float*)d_ws;
    float* mxr  = ws;                  // [ROWS]
    float* mxt  = mxr + ROWS;          // [ROWS]
    float* grgb = mxt + ROWS;          // [ROWS]
    float* gtir = grgb + ROWS;         // [ROWS]

    v4f* outTir = (v4f*)d_out;         // tir_col first per reference return
    v4f* outRgb = outTir + N4PT;

    // K1: rowmax + stage. 2*ROWS waves, 4 waves per 256-thread block.
    int k1_blocks = (2 * ROWS) / 4;    // 49152
    k_stage<<<k1_blocks, 256, 0, stream>>>(attn_rgb, attn_tir, mxr, mxt,
                                           outTir, outRgb);

    // K2: one block per 4 (b,h)
    k_mlp<<<BH / 4, 256, 0, stream>>>(gidx, mxr, mxt, ln_g, ln_b, W1, b1, W2, b2,
                                      grgb, gtir);

    // K3: in-place scale. Same geometry as K1.
    k_scale<<<k1_blocks, 256, 0, stream>>>(grgb, gtir, outTir, outRgb);
}

// Round 5
// 163.354 us; speedup vs baseline: 1.6110x; 1.1261x over previous
//
#include <hip/hip_runtime.h>
#include <hip/hip_bf16.h>
#include <math.h>

// Problem constants
#define BB   32
#define HN   12
#define N1   256
#define N2   320
#define SS   256
#define BH   (BB*HN)                 // 384
#define R4   (N2/4)                  // 80 float4 per row
#define SLICE4 ((size_t)N1*R4)       // float4 per (b,h) slice = 20480

typedef float v4f __attribute__((ext_vector_type(4)));

// Fully fused: one block per (b,h).
//  Phase 1: read own slice (rgb+tir), row maxes -> LDS.  (inputs allocate L3)
//  Phase 2: scatter -> LayerNorm(512) -> Linear+ReLU -> Linear+Sigmoid -> per-row gates.
//  Phase 3: re-read own slice (should be L3/L2-hot, ~1 us old), scale, NT-store.
__global__ __launch_bounds__(256, 2) void k_fused(
    const float* __restrict__ rgb, const float* __restrict__ tir,
    const int*   __restrict__ gidx,
    const float* __restrict__ ln_g, const float* __restrict__ ln_b,
    const float* __restrict__ W1,  const float* __restrict__ b1,
    const float* __restrict__ W2,  const float* __restrict__ b2,
    v4f* __restrict__ outTir, v4f* __restrict__ outRgb)
{
    __shared__ float mxs[2 * SS];    // row maxes: rgb [0,256), tir [256,512)
    __shared__ float v[2 * SS];      // scattered -> normalized vector
    __shared__ float hs[SS];         // hidden relu
    __shared__ float gs[2 * SS];     // sigmoid gates
    __shared__ float growR[SS];      // per-row gate, rgb
    __shared__ float growT[SS];      // per-row gate, tir
    __shared__ int   sidx_s[SS];
    __shared__ float red[8];

    const int bh   = (int)blockIdx.x;    // 0..383
    const int b    = bh / HN;
    const int t    = (int)threadIdx.x;   // 0..255
    const int w    = t >> 6;             // wave 0..3
    const int lane = t & 63;

    sidx_s[t] = gidx[b * SS + t];
    v[t] = 0.f; v[t + SS] = 0.f;

    const v4f* srcR = (const v4f*)rgb + (size_t)bh * SLICE4;
    const v4f* srcT = (const v4f*)tir + (size_t)bh * SLICE4;

    // ---- Phase 1: row maxes; wave w handles rows [w*64, w*64+64) ----
    for (int r = w * 64; r < w * 64 + 64; ++r) {
        const v4f* pR = srcR + (size_t)r * R4;
        const v4f* pT = srcT + (size_t)r * R4;
        v4f aR = pR[lane], aT = pT[lane];
        float mR = fmaxf(fmaxf(aR.x, aR.y), fmaxf(aR.z, aR.w));
        float mT = fmaxf(fmaxf(aT.x, aT.y), fmaxf(aT.z, aT.w));
        if (lane < 16) {
            v4f bR = pR[64 + lane], bT = pT[64 + lane];
            mR = fmaxf(mR, fmaxf(fmaxf(bR.x, bR.y), fmaxf(bR.z, bR.w)));
            mT = fmaxf(mT, fmaxf(fmaxf(bT.x, bT.y), fmaxf(bT.z, bT.w)));
        }
#pragma unroll
        for (int off = 32; off; off >>= 1) {
            mR = fmaxf(mR, __shfl_xor(mR, off));
            mT = fmaxf(mT, __shfl_xor(mT, off));
        }
        if (lane == 0) { mxs[r] = mR; mxs[SS + r] = mT; }
    }
    __syncthreads();

    // ---- Phase 2a: scatter (per-batch permutation -> collision-free) ----
    {
        int sidx = sidx_s[t];
        v[sidx]      = mxs[t];
        v[sidx + SS] = mxs[SS + t];
    }
    __syncthreads();

    // ---- Phase 2b: LayerNorm over 512 ----
    {
        float x0 = v[t], x1 = v[t + SS];
        float s  = x0 + x1;
        float sq = x0 * x0 + x1 * x1;
#pragma unroll
        for (int off = 32; off; off >>= 1) {
            s  += __shfl_xor(s, off);
            sq += __shfl_xor(sq, off);
        }
        if (lane == 0) { red[w] = s; red[4 + w] = sq; }
        __syncthreads();
        s  = red[0] + red[1] + red[2] + red[3];
        sq = red[4] + red[5] + red[6] + red[7];
        const float mu   = s * (1.f / 512.f);
        const float var  = sq * (1.f / 512.f) - mu * mu;
        const float rstd = rsqrtf(var + 1e-5f);
        v[t]      = (x0 - mu) * rstd * ln_g[t]      + ln_b[t];
        v[t + SS] = (x1 - mu) * rstd * ln_g[t + SS] + ln_b[t + SS];
    }
    __syncthreads();

    // ---- Phase 2c: GEMM1  hs[t] = relu(sum_e v[e]*W1[e*256+t] + b1[t]) ----
    {
        float a0 = b1[t], a1 = 0.f;
#pragma unroll 8
        for (int e = 0; e < SS; ++e)       a0 = fmaf(v[e], W1[e * SS + t], a0);
#pragma unroll 8
        for (int e = SS; e < 2 * SS; ++e)  a1 = fmaf(v[e], W1[e * SS + t], a1);
        hs[t] = fmaxf(a0 + a1, 0.f);
    }
    __syncthreads();

    // ---- Phase 2d: GEMM2  gs[.] = sigmoid(sum_f hs[f]*W2[f*512+.] + b2) ----
    {
        float lo0 = b2[t], lo1 = 0.f, hi0 = b2[t + SS], hi1 = 0.f;
#pragma unroll 8
        for (int f = 0; f < 128; ++f) {
            float hv = hs[f];
            lo0 = fmaf(hv, W2[f * 2 * SS + t],      lo0);
            hi0 = fmaf(hv, W2[f * 2 * SS + t + SS], hi0);
        }
#pragma unroll 8
        for (int f = 128; f < SS; ++f) {
            float hv = hs[f];
            lo1 = fmaf(hv, W2[f * 2 * SS + t],      lo1);
            hi1 = fmaf(hv, W2[f * 2 * SS + t + SS], hi1);
        }
        gs[t]      = 1.f / (1.f + expf(-(lo0 + lo1)));
        gs[t + SS] = 1.f / (1.f + expf(-(hi0 + hi1)));
    }
    __syncthreads();

    // ---- Phase 2e: gather per-row gates ----
    growR[t] = gs[sidx_s[t]];
    growT[t] = gs[sidx_s[t] + SS];
    __syncthreads();

    // ---- Phase 3: re-read own slice (hot), scale, NT-store ----
    v4f* dstR = outRgb + (size_t)bh * SLICE4;
    v4f* dstT = outTir + (size_t)bh * SLICE4;
    for (int r = w * 64; r < w * 64 + 64; ++r) {
        float gR = growR[r], gT = growT[r];
        const v4f* pR = srcR + (size_t)r * R4;
        const v4f* pT = srcT + (size_t)r * R4;
        v4f aR = pR[lane], aT = pT[lane];
        __builtin_nontemporal_store(aR * gR, dstR + (size_t)r * R4 + lane);
        __builtin_nontemporal_store(aT * gT, dstT + (size_t)r * R4 + lane);
        if (lane < 16) {
            v4f bR = pR[64 + lane], bT = pT[64 + lane];
            __builtin_nontemporal_store(bR * gR, dstR + (size_t)r * R4 + 64 + lane);
            __builtin_nontemporal_store(bT * gT, dstT + (size_t)r * R4 + 64 + lane);
        }
    }
}

extern "C" void kernel_launch(void* const* d_in, const int* in_sizes, int n_in,
                              void* d_out, int out_size, void* d_ws, size_t ws_size,
                              hipStream_t stream)
{
    const float* attn_rgb = (const float*)d_in[0];
    const float* attn_tir = (const float*)d_in[1];
    const int*   gidx     = (const int*)  d_in[2];
    const float* ln_g     = (const float*)d_in[3];
    const float* ln_b     = (const float*)d_in[4];
    const float* W1       = (const float*)d_in[5];
    const float* b1       = (const float*)d_in[6];
    const float* W2       = (const float*)d_in[7];
    const float* b2       = (const float*)d_in[8];

    v4f* outTir = (v4f*)d_out;               // tir_col first per reference
    v4f* outRgb = outTir + (size_t)BH * SLICE4;

    k_fused<<<BH, 256, 0, stream>>>(attn_rgb, attn_tir, gidx, ln_g, ln_b,
                                    W1, b1, W2, b2, outTir, outRgb);
}

// Round 6
// 138.878 us; speedup vs baseline: 1.8950x; 1.1762x over previous
//
#include <hip/hip_runtime.h>
#include <hip/hip_bf16.h>
#include <math.h>

// Problem constants
#define BB   32
#define HN   12
#define N1   256
#define N2   320
#define SS   256
#define BH   (BB*HN)                 // 384
#define R4   (N2/4)                  // 80 float4 per row
#define SLICE4 ((size_t)N1*R4)       // float4 per (b,h) slice = 20480

typedef float v4f __attribute__((ext_vector_type(4)));

// Fully fused: one block per (b,h).
//  Phase 1: read own slice (rgb+tir) with deep load batching, row maxes -> LDS.
//  Phase 2: scatter -> LayerNorm(512) -> Linear+ReLU -> Linear+Sigmoid -> gates.
//  Phase 3: re-read own slice flat/coalesced (L3-hot), scale, NT-store.
__global__ __launch_bounds__(256, 2) void k_fused(
    const float* __restrict__ rgb, const float* __restrict__ tir,
    const int*   __restrict__ gidx,
    const float* __restrict__ ln_g, const float* __restrict__ ln_b,
    const float* __restrict__ W1,  const float* __restrict__ b1,
    const float* __restrict__ W2,  const float* __restrict__ b2,
    v4f* __restrict__ outTir, v4f* __restrict__ outRgb)
{
    __shared__ float mxs[2 * SS];    // row maxes: rgb [0,256), tir [256,512)
    __shared__ float v[2 * SS];      // scattered -> normalized vector
    __shared__ float hs[SS];         // hidden relu
    __shared__ float gs[2 * SS];     // sigmoid gates
    __shared__ float growR[SS];      // per-row gate, rgb
    __shared__ float growT[SS];      // per-row gate, tir
    __shared__ int   sidx_s[SS];
    __shared__ float red[8];

    const int bh   = (int)blockIdx.x;    // 0..383
    const int b    = bh / HN;
    const int t    = (int)threadIdx.x;   // 0..255
    const int w    = t >> 6;             // wave 0..3
    const int lane = t & 63;

    sidx_s[t] = gidx[b * SS + t];
    v[t] = 0.f; v[t + SS] = 0.f;

    const v4f* srcR = (const v4f*)rgb + (size_t)bh * SLICE4;
    const v4f* srcT = (const v4f*)tir + (size_t)bh * SLICE4;

    // ---- Phase 1: row maxes; wave w handles rows [w*64, w*64+64) ----
    // 4 rows per group; 16 independent loads issued before any reduction.
    // Tail f4s [64,80) loaded unconditionally via (lane&15) duplication:
    // duplicate lanes can't change a max and coalesce to the same lines.
    for (int rr = 0; rr < 64; rr += 4) {
        const int r = w * 64 + rr;
        v4f aR[4], bRv[4], aT[4], bTv[4];
#pragma unroll
        for (int q = 0; q < 4; ++q) {
            const v4f* pR = srcR + (size_t)(r + q) * R4;
            const v4f* pT = srcT + (size_t)(r + q) * R4;
            aR[q]  = pR[lane];
            bRv[q] = pR[64 + (lane & 15)];
            aT[q]  = pT[lane];
            bTv[q] = pT[64 + (lane & 15)];
        }
#pragma unroll
        for (int q = 0; q < 4; ++q) {
            float mR = fmaxf(fmaxf(fmaxf(aR[q].x, aR[q].y), fmaxf(aR[q].z, aR[q].w)),
                             fmaxf(fmaxf(bRv[q].x, bRv[q].y), fmaxf(bRv[q].z, bRv[q].w)));
            float mT = fmaxf(fmaxf(fmaxf(aT[q].x, aT[q].y), fmaxf(aT[q].z, aT[q].w)),
                             fmaxf(fmaxf(bTv[q].x, bTv[q].y), fmaxf(bTv[q].z, bTv[q].w)));
#pragma unroll
            for (int off = 32; off; off >>= 1) {
                mR = fmaxf(mR, __shfl_xor(mR, off));
                mT = fmaxf(mT, __shfl_xor(mT, off));
            }
            if (lane == 0) { mxs[r + q] = mR; mxs[SS + r + q] = mT; }
        }
    }
    __syncthreads();

    // ---- Phase 2a: scatter (per-batch permutation -> collision-free) ----
    {
        int sidx = sidx_s[t];
        v[sidx]      = mxs[t];
        v[sidx + SS] = mxs[SS + t];
    }
    __syncthreads();

    // ---- Phase 2b: LayerNorm over 512 ----
    {
        float x0 = v[t], x1 = v[t + SS];
        float s  = x0 + x1;
        float sq = x0 * x0 + x1 * x1;
#pragma unroll
        for (int off = 32; off; off >>= 1) {
            s  += __shfl_xor(s, off);
            sq += __shfl_xor(sq, off);
        }
        if (lane == 0) { red[w] = s; red[4 + w] = sq; }
        __syncthreads();
        s  = red[0] + red[1] + red[2] + red[3];
        sq = red[4] + red[5] + red[6] + red[7];
        const float mu   = s * (1.f / 512.f);
        const float var  = sq * (1.f / 512.f) - mu * mu;
        const float rstd = rsqrtf(var + 1e-5f);
        v[t]      = (x0 - mu) * rstd * ln_g[t]      + ln_b[t];
        v[t + SS] = (x1 - mu) * rstd * ln_g[t + SS] + ln_b[t + SS];
    }
    __syncthreads();

    // ---- Phase 2c: GEMM1  hs[t] = relu(sum_e v[e]*W1[e*256+t] + b1[t]) ----
    {
        float a0 = b1[t], a1 = 0.f;
#pragma unroll 8
        for (int e = 0; e < SS; ++e)       a0 = fmaf(v[e], W1[e * SS + t], a0);
#pragma unroll 8
        for (int e = SS; e < 2 * SS; ++e)  a1 = fmaf(v[e], W1[e * SS + t], a1);
        hs[t] = fmaxf(a0 + a1, 0.f);
    }
    __syncthreads();

    // ---- Phase 2d: GEMM2  gs[.] = sigmoid(sum_f hs[f]*W2[f*512+.] + b2) ----
    {
        float lo0 = b2[t], lo1 = 0.f, hi0 = b2[t + SS], hi1 = 0.f;
#pragma unroll 8
        for (int f = 0; f < 128; ++f) {
            float hv = hs[f];
            lo0 = fmaf(hv, W2[f * 2 * SS + t],      lo0);
            hi0 = fmaf(hv, W2[f * 2 * SS + t + SS], hi0);
        }
#pragma unroll 8
        for (int f = 128; f < SS; ++f) {
            float hv = hs[f];
            lo1 = fmaf(hv, W2[f * 2 * SS + t],      lo1);
            hi1 = fmaf(hv, W2[f * 2 * SS + t + SS], hi1);
        }
        gs[t]      = 1.f / (1.f + expf(-(lo0 + lo1)));
        gs[t + SS] = 1.f / (1.f + expf(-(hi0 + hi1)));
    }
    __syncthreads();

    // ---- Phase 2e: gather per-row gates ----
    growR[t] = gs[sidx_s[t]];
    growT[t] = gs[sidx_s[t] + SS];
    __syncthreads();

    // ---- Phase 3: flat coalesced re-read (hot), scale, NT-store ----
    {
        v4f* dstR = outRgb + (size_t)bh * SLICE4;
        v4f* dstT = outTir + (size_t)bh * SLICE4;
        for (int k = 0; k < 80; k += 8) {
            v4f aR[8], aT[8];
#pragma unroll
            for (int q = 0; q < 8; ++q) {
                unsigned i = (unsigned)(k + q) * 256u + (unsigned)t;
                aR[q] = srcR[i];
                aT[q] = srcT[i];
            }
#pragma unroll
            for (int q = 0; q < 8; ++q) {
                unsigned i   = (unsigned)(k + q) * 256u + (unsigned)t;
                unsigned row = i / 80u;
                v4f oR = aR[q] * growR[row];
                v4f oT = aT[q] * growT[row];
                __builtin_nontemporal_store(oT, dstT + i);
                __builtin_nontemporal_store(oR, dstR + i);
            }
        }
    }
}

extern "C" void kernel_launch(void* const* d_in, const int* in_sizes, int n_in,
                              void* d_out, int out_size, void* d_ws, size_t ws_size,
                              hipStream_t stream)
{
    const float* attn_rgb = (const float*)d_in[0];
    const float* attn_tir = (const float*)d_in[1];
    const int*   gidx     = (const int*)  d_in[2];
    const float* ln_g     = (const float*)d_in[3];
    const float* ln_b     = (const float*)d_in[4];
    const float* W1       = (const float*)d_in[5];
    const float* b1       = (const float*)d_in[6];
    const float* W2       = (const float*)d_in[7];
    const float* b2       = (const float*)d_in[8];

    v4f* outTir = (v4f*)d_out;               // tir_col first per reference
    v4f* outRgb = outTir + (size_t)BH * SLICE4;

    k_fused<<<BH, 256, 0, stream>>>(attn_rgb, attn_tir, gidx, ln_g, ln_b,
                                    W1, b1, W2, b2, outTir, outRgb);
}